// Round 1
// 465.591 us; speedup vs baseline: 1.0001x; 1.0001x over previous
//
#include <hip/hip_runtime.h>
#include <math.h>

#define D 64

typedef __attribute__((ext_vector_type(8))) short bf16x8;
typedef __attribute__((ext_vector_type(4))) float f32x4;

static __device__ __forceinline__ unsigned short f2bf(float f) {
    unsigned int u = __float_as_uint(f);
    unsigned int r = (u + 0x7FFFu + ((u >> 16) & 1u)) >> 16;  // RNE
    return (unsigned short)r;
}
static __device__ __forceinline__ float bf2f(unsigned short h) {
    return __uint_as_float(((unsigned int)h) << 16);
}

#if defined(__has_builtin)
#if __has_builtin(__builtin_amdgcn_cvt_pk_bf16_f32)
#define HAVE_PK_BF16 1
#endif
#endif

static __device__ __forceinline__ unsigned int pk2bf(float a, float b) {
#ifdef HAVE_PK_BF16
    auto v = __builtin_amdgcn_cvt_pk_bf16_f32(a, b);   // low=a, high=b
    return *(unsigned int*)&v;
#else
    return (unsigned int)f2bf(a) | ((unsigned int)f2bf(b) << 16);
#endif
}

// tanh(x) = 1 - 2/(e^{2x}+1); inf-safe at extremes (no clamp needed)
static __device__ __forceinline__ float fast_tanh(float x) {
    float e = __expf(2.f * x);
    float r = __builtin_amdgcn_rcpf(e + 1.f);
    return 1.f - 2.f * r;
}

typedef __attribute__((address_space(1))) const unsigned int as1_uint;
typedef __attribute__((address_space(3))) unsigned int as3_uint;
static __device__ __forceinline__ void dma16(const void* g, void* l) {
    // async global->LDS, 16B/lane; LDS dest = uniform base + lane*16
    __builtin_amdgcn_global_load_lds((as1_uint*)g, (as3_uint*)l, 16, 0, 0);
}

// ---------------- pre-split W into MFMA B-fragment-ordered hi/lo bf16 arrays.
// B1 (GEMM1, P=feat@W):   element W[r][d=kb*32+q*8+j][o=c*16+m]
// B2 (GEMM2, V=u@W^T):    element W[r][d=c*16+m][o=kb*32+q*8+j]
// layout: [r][c][kb][lane=q*16+m][j]  -> chunk (r, c*2+kb) = 64 lanes x 16B
__global__ __launch_bounds__(256) void k_wsplit(const float* __restrict__ W,
                                                unsigned short* __restrict__ B1h,
                                                unsigned short* __restrict__ B1l,
                                                unsigned short* __restrict__ B2h,
                                                unsigned short* __restrict__ B2l,
                                                int R) {
    int idx = blockIdx.x * 256 + threadIdx.x;
    int per_g = R * 512;
    if (idx >= 2 * per_g) return;
    int g = idx / per_g;
    int rest = idx % per_g;
    int r = rest >> 9;
    int rest2 = rest & 511;
    int c = rest2 >> 7;
    int kb = (rest2 >> 6) & 1;
    int lane = rest2 & 63;
    int m = lane & 15, q = lane >> 4;
    bf16x8 hv, lv;
    #pragma unroll
    for (int j = 0; j < 8; ++j) {
        float v;
        if (g == 0) v = W[(size_t)r * 4096 + (kb * 32 + q * 8 + j) * 64 + (c * 16 + m)];
        else        v = W[(size_t)r * 4096 + (c * 16 + m) * 64 + (kb * 32 + q * 8 + j)];
        unsigned short h = f2bf(v);
        hv[j] = (short)h;
        lv[j] = (short)f2bf(v - bf2f(h));
    }
    size_t off = ((((size_t)r * 4 + c) * 2 + kb) * 64 + lane) * 8;
    unsigned short* ph = (g == 0) ? B1h : B2h;
    unsigned short* pl = (g == 0) ? B1l : B2l;
    *(bf16x8*)&ph[off] = hv;
    *(bf16x8*)&pl[off] = lv;
}

// ---------------- pre-split W1/W2 (for k_final): out = x @ Wk^T.
__global__ __launch_bounds__(256) void k_wsplit2(const float* __restrict__ W1,
                                                 const float* __restrict__ W2,
                                                 unsigned short* __restrict__ F1h,
                                                 unsigned short* __restrict__ F1l,
                                                 unsigned short* __restrict__ F2h,
                                                 unsigned short* __restrict__ F2l) {
    int idx = blockIdx.x * 256 + threadIdx.x;
    if (idx >= 1024) return;
    int g = idx >> 9;
    int rest2 = idx & 511;
    int c = rest2 >> 7;
    int kb = (rest2 >> 6) & 1;
    int lane = rest2 & 63;
    int m = lane & 15, q = lane >> 4;
    const float* W = g ? W2 : W1;
    bf16x8 hv, lv;
    #pragma unroll
    for (int j = 0; j < 8; ++j) {
        float v = W[(c * 16 + m) * 64 + kb * 32 + q * 8 + j];
        unsigned short h = f2bf(v);
        hv[j] = (short)h;
        lv[j] = (short)f2bf(v - bf2f(h));
    }
    size_t off = (((size_t)c * 2 + kb) * 64 + lane) * 8;
    unsigned short* ph = g ? F2h : F1h;
    unsigned short* pl = g ? F2l : F1l;
    *(bf16x8*)&ph[off] = hv;
    *(bf16x8*)&pl[off] = lv;
}

// ---------------- fused proj+V, two-phase pipelined over a single B buffer.
// Rows 0-15 = B1(r) (GEMM1 only), rows 16-31 = B2(r) (GEMM2 only).
// Per r: GEMM1(both s) | bar | stage B1(r+1) | epi | GEMM2(both s)+store |
//        bar | stage B2(r+1).  Each DMA half overlaps a full compute phase.
// B-fragment LDS reads hoisted over s: 36 ds_read_b128/wave/r (was 66).
// LDS = 32KB B + 16KB Us = 48KB -> 3 blocks/CU (grid is ~3.05/CU anyway).
__global__ __launch_bounds__(256, 3) void k_projv(const float* __restrict__ feat,
                                                  const unsigned short* __restrict__ B1h,
                                                  const unsigned short* __restrict__ B1l,
                                                  const unsigned short* __restrict__ B2h,
                                                  const unsigned short* __restrict__ B2l,
                                                  const float* __restrict__ emb,
                                                  unsigned short* __restrict__ V,
                                                  int N, int R) {
    const int n0 = blockIdx.x * 128;
    __shared__ __align__(16) unsigned short Bbuf[32][512];      // 32 KB
    __shared__ __align__(16) unsigned short Us[4][2][1024];     // 16 KB (2KB/wave/s)
    const int t = threadIdx.x;
    const int lane = t & 63, w = t >> 6;
    const int m = lane & 15, q = lane >> 4;

    // ---- A-frags direct from global, split hi/lo in-register
    bf16x8 ah[2][2], al[2][2];
    #pragma unroll
    for (int s = 0; s < 2; ++s) {
        int n = n0 + w * 32 + s * 16 + m;
        const float* rowp = feat + (size_t)n * D;
        #pragma unroll
        for (int kb = 0; kb < 2; ++kb) {
            int d0 = kb * 32 + q * 8;
            float4 v0 = make_float4(0.f, 0.f, 0.f, 0.f), v1 = v0;
            if (n < N) { v0 = *(const float4*)(rowp + d0); v1 = *(const float4*)(rowp + d0 + 4); }
            float vals[8] = {v0.x, v0.y, v0.z, v0.w, v1.x, v1.y, v1.z, v1.w};
            bf16x8 hv, lv;
            #pragma unroll
            for (int j = 0; j < 8; ++j) {
                unsigned short h = f2bf(vals[j]);
                hv[j] = (short)h;
                lv[j] = (short)f2bf(vals[j] - bf2f(h));
            }
            ah[s][kb] = hv; al[s][kb] = lv;
        }
    }

    // stage one 16KB half (B1 -> rows 0-15, or B2 -> rows 16-31), all 4 waves:
    // wave w takes 4 of the 16 1KB chunks.
    auto stage_half = [&](int r, int half) {
        const unsigned short* arr = half ? ((w < 2) ? B2h : B2l)
                                         : ((w < 2) ? B1h : B1l);
        const unsigned short* gp = arr + (size_t)r * 4096 + (size_t)(w & 1) * 2048 + lane * 8;
        unsigned short* lp = &Bbuf[half * 16 + (w >> 1) * 8 + (w & 1) * 4][0];
        #pragma unroll
        for (int i = 0; i < 4; ++i)
            dma16(gp + i * 512, lp + i * 512);
    };

    stage_half(0, 0);
    stage_half(0, 1);
    __syncthreads();

    for (int r = 0; r < R; ++r) {
        float em[4];
        #pragma unroll
        for (int c = 0; c < 4; ++c) em[c] = emb[r * 64 + c * 16 + m];

        // ---------- GEMM1 (both s): P = feat @ W_r (3-term split), B-frags hoisted
        f32x4 acc[4][2];
        #pragma unroll
        for (int c = 0; c < 4; ++c)
            #pragma unroll
            for (int s = 0; s < 2; ++s) acc[c][s] = (f32x4){0.f, 0.f, 0.f, 0.f};
        #pragma unroll
        for (int c = 0; c < 4; ++c) {
            bf16x8 bh[2], bl[2];
            #pragma unroll
            for (int kb = 0; kb < 2; ++kb) {
                bh[kb] = *(const bf16x8*)&Bbuf[c * 2 + kb][lane * 8];
                bl[kb] = *(const bf16x8*)&Bbuf[8 + c * 2 + kb][lane * 8];
            }
            #pragma unroll
            for (int s = 0; s < 2; ++s)
                #pragma unroll
                for (int kb = 0; kb < 2; ++kb) {
                    acc[c][s] = __builtin_amdgcn_mfma_f32_16x16x32_bf16(ah[s][kb], bh[kb], acc[c][s], 0, 0, 0);
                    acc[c][s] = __builtin_amdgcn_mfma_f32_16x16x32_bf16(al[s][kb], bh[kb], acc[c][s], 0, 0, 0);
                    acc[c][s] = __builtin_amdgcn_mfma_f32_16x16x32_bf16(ah[s][kb], bl[kb], acc[c][s], 0, 0, 0);
                }
        }

        __syncthreads();                      // all waves done reading rows 0-15
        if (r + 1 < R) stage_half(r + 1, 0);  // B1(r+1) DMA overlaps epi+GEMM2

        // ---------- epilogue: u = tanh(P+emb) -> swizzled wave-private Us (both s)
        #pragma unroll
        for (int s = 0; s < 2; ++s)
            #pragma unroll
            for (int c = 0; c < 4; ++c) {
                int o = c * 16 + m;
                int kb2 = o >> 5;
                int q2 = (o >> 3) & 3;
                int j = o & 7;
                int Fb = kb2 * 64 + q2 * 16 + q * 4;
                #pragma unroll
                for (int i = 0; i < 4; i += 2) {
                    float t0 = fast_tanh(acc[c][s][i] + em[c]);
                    float t1 = fast_tanh(acc[c][s][i + 1] + em[c]);
                    unsigned int pk = pk2bf(t0, t1);
                    Us[w][s][((Fb + i) ^ q2) * 8 + j]     = (unsigned short)(pk & 0xFFFF);
                    Us[w][s][((Fb + i + 1) ^ q2) * 8 + j] = (unsigned short)(pk >> 16);
                }
            }

        // ---------- GEMM2 (both s): V = u @ W_r^T (2-term split), B-frags hoisted
        bf16x8 ua[2][2];
        #pragma unroll
        for (int s = 0; s < 2; ++s)
            #pragma unroll
            for (int kb = 0; kb < 2; ++kb) {
                int F = kb * 64 + lane;
                ua[s][kb] = *(const bf16x8*)&Us[w][s][(F ^ (lane >> 4)) * 8];
            }
        f32x4 acc2[4][2];
        #pragma unroll
        for (int c = 0; c < 4; ++c)
            #pragma unroll
            for (int s = 0; s < 2; ++s) acc2[c][s] = (f32x4){0.f, 0.f, 0.f, 0.f};
        #pragma unroll
        for (int c = 0; c < 4; ++c) {
            bf16x8 bh[2], bl[2];
            #pragma unroll
            for (int kb = 0; kb < 2; ++kb) {
                bh[kb] = *(const bf16x8*)&Bbuf[16 + c * 2 + kb][lane * 8];
                bl[kb] = *(const bf16x8*)&Bbuf[24 + c * 2 + kb][lane * 8];
            }
            #pragma unroll
            for (int s = 0; s < 2; ++s)
                #pragma unroll
                for (int kb = 0; kb < 2; ++kb) {
                    acc2[c][s] = __builtin_amdgcn_mfma_f32_16x16x32_bf16(ua[s][kb], bh[kb], acc2[c][s], 0, 0, 0);
                    acc2[c][s] = __builtin_amdgcn_mfma_f32_16x16x32_bf16(ua[s][kb], bl[kb], acc2[c][s], 0, 0, 0);
                }
        }

        // ---------- store V permuted: Vstore[n][r][m*4+c] (8B/lane)
        #pragma unroll
        for (int s = 0; s < 2; ++s)
            #pragma unroll
            for (int i = 0; i < 4; ++i) {
                int n = n0 + w * 32 + s * 16 + q * 4 + i;
                if (n < N) {
                    uint2 pv;
                    pv.x = pk2bf(acc2[0][s][i], acc2[1][s][i]);
                    pv.y = pk2bf(acc2[2][s][i], acc2[3][s][i]);
                    *(uint2*)&V[((size_t)n * R + r) * 64 + m * 4] = pv;
                }
            }

        __syncthreads();                      // rows16-31 reads done; B1 DMA drained
        if (r + 1 < R) stage_half(r + 1, 1);  // B2(r+1) DMA overlaps next GEMM1
    }
}

// ---------------- histogram of dst
__global__ __launch_bounds__(256) void k_hist(const int* __restrict__ dst, int* __restrict__ deg, int E) {
    int e = blockIdx.x * 256 + threadIdx.x;
    if (e < E) atomicAdd(&deg[dst[e]], 1);
}

// ---------------- scan step 1
__global__ __launch_bounds__(1024) void k_scan1(const int* __restrict__ deg, int* __restrict__ tscan,
                                                int* __restrict__ bsum, int N) {
    __shared__ int s[1024];
    const int t = threadIdx.x;
    const int i = blockIdx.x * 1024 + t;
    int v = (i < N) ? deg[i] : 0;
    s[t] = v;
    __syncthreads();
    for (int off = 1; off < 1024; off <<= 1) {
        int tmp = (t >= off) ? s[t - off] : 0;
        __syncthreads();
        s[t] += tmp;
        __syncthreads();
    }
    if (i < N) tscan[i] = s[t];
    if (t == 1023) bsum[blockIdx.x] = s[1023];
}

// ---------------- scan step 2
__global__ __launch_bounds__(1024) void k_scan2(const int* __restrict__ bsum, int* __restrict__ bofs, int NB) {
    __shared__ int s[1024];
    const int t = threadIdx.x;
    int carry = 0;
    for (int b0 = 0; b0 < NB; b0 += 1024) {
        int i = b0 + t;
        int v = (i < NB) ? bsum[i] : 0;
        s[t] = v;
        __syncthreads();
        for (int off = 1; off < 1024; off <<= 1) {
            int tmp = (t >= off) ? s[t - off] : 0;
            __syncthreads();
            s[t] += tmp;
            __syncthreads();
        }
        if (i < NB) bofs[i] = carry + s[t] - v;
        int tot = s[1023];
        __syncthreads();
        carry += tot;
    }
}

// ---------------- scan step 3
__global__ __launch_bounds__(256) void k_scan3(const int* __restrict__ tscan, const int* __restrict__ bofs,
                                               int* __restrict__ offsets, int* __restrict__ cursor, int N) {
    int i = blockIdx.x * 256 + threadIdx.x;
    if (i <= N) {
        int v = (i == 0) ? 0 : (tscan[i - 1] + bofs[(i - 1) >> 10]);
        offsets[i] = v;
        if (i < N) cursor[i] = v;
    }
}

// ---------------- scatter edges into dst-sorted order
__global__ __launch_bounds__(256) void k_scatter(const int* __restrict__ src, const int* __restrict__ dst,
                                                 const int* __restrict__ etype, int* __restrict__ cursor,
                                                 int* __restrict__ spack, int E) {
    int e = blockIdx.x * 256 + threadIdx.x;
    if (e < E) {
        int d = dst[e];
        int p = atomicAdd(&cursor[d], 1);
        spack[p] = src[e] | (etype[e] << 20);
    }
}

// ---------------- fused att + softmax + aggregation: 4 edges per wave-iteration.
__global__ __launch_bounds__(256) void k_fused2(const unsigned short* __restrict__ V,
                                                const float* __restrict__ feat,
                                                const int* __restrict__ offsets,
                                                const int* __restrict__ spack,
                                                float* __restrict__ h_nb,
                                                int N, int R) {
    const int lane = threadIdx.x & 63;
    const int wav  = threadIdx.x >> 6;
    const int g    = lane >> 4;
    const int k    = lane & 15;
    const int n = blockIdx.x * 4 + wav;
    __shared__ float vlds[4][1024];
    if (n >= N) return;

    const unsigned int* v32 = (const unsigned int*)(V + (size_t)n * R * D);
    #pragma unroll
    for (int j = 0; j < 8; ++j) {
        int uidx = j * 64 + lane;
        unsigned int u = v32[uidx];
        int r  = uidx >> 5;
        int k2 = uidx & 31;
        int mm = k2 >> 1;
        int cc = (k2 & 1) * 2;
        int o  = cc * 16 + mm;
        vlds[wav][r * 64 + o]      = bf2f((unsigned short)(u & 0xFFFF));
        vlds[wav][r * 64 + o + 16] = bf2f((unsigned short)(u >> 16));
    }

    const int beg = offsets[n], end = offsets[n + 1];
    float m = -INFINITY, l = 0.f;
    float4 acc = make_float4(0.f, 0.f, 0.f, 0.f);

    if (beg < end) {
        int e = beg + g;
        bool ok = e < end;
        int pk = spack[ok ? e : (end - 1)];
        float4 f = *(const float4*)&feat[(size_t)(pk & 0xFFFFF) * D + k * 4];

        for (int i = beg; i < end; i += 4) {
            const int   et  = pk >> 20;
            const float4 fc = f;
            const bool  okc = ok;
            int e2 = i + 4 + g;
            ok = e2 < end;
            pk = spack[ok ? e2 : (end - 1)];
            f = *(const float4*)&feat[(size_t)(pk & 0xFFFFF) * D + k * 4];

            float4 v = *(const float4*)&vlds[wav][et * 64 + k * 4];
            float p = fc.x * v.x + fc.y * v.y + fc.z * v.z + fc.w * v.w;
            p += __shfl_xor(p, 1, 64);
            p += __shfl_xor(p, 2, 64);
            p += __shfl_xor(p, 4, 64);
            p += __shfl_xor(p, 8, 64);
            p = okc ? p : -INFINITY;
            float tmx = fmaxf(p, __shfl_xor(p, 16, 64));
            float nm4 = fmaxf(tmx, __shfl_xor(tmx, 32, 64));
            float nm  = fmaxf(m, nm4);
            float scale = __expf(m - nm);
            float wg    = __expf(p - nm);
            float sw = wg + __shfl_xor(wg, 16, 64);
            sw += __shfl_xor(sw, 32, 64);
            l = l * scale + sw;
            acc.x = acc.x * scale + wg * fc.x;
            acc.y = acc.y * scale + wg * fc.y;
            acc.z = acc.z * scale + wg * fc.z;
            acc.w = acc.w * scale + wg * fc.w;
            m = nm;
        }
        acc.x += __shfl_xor(acc.x, 16, 64);
        acc.y += __shfl_xor(acc.y, 16, 64);
        acc.z += __shfl_xor(acc.z, 16, 64);
        acc.w += __shfl_xor(acc.w, 16, 64);
        acc.x += __shfl_xor(acc.x, 32, 64);
        acc.y += __shfl_xor(acc.y, 32, 64);
        acc.z += __shfl_xor(acc.z, 32, 64);
        acc.w += __shfl_xor(acc.w, 32, 64);
        float inv = 1.f / l;
        acc.x *= inv; acc.y *= inv; acc.z *= inv; acc.w *= inv;
    }
    if (lane < 16)
        *(float4*)&h_nb[(size_t)n * D + k * 4] = acc;
}

// ---------------- final via MFMA: out = lrelu((f+h)@W1^T) + lrelu((f*h)@W2^T)
__global__ __launch_bounds__(256, 2) void k_final(const float* __restrict__ feat,
                                                  const float* __restrict__ h_nb,
                                                  const unsigned short* __restrict__ F1h,
                                                  const unsigned short* __restrict__ F1l,
                                                  const unsigned short* __restrict__ F2h,
                                                  const unsigned short* __restrict__ F2l,
                                                  float* __restrict__ out, int N) {
    const int n0 = blockIdx.x * 128;
    __shared__ __align__(16) unsigned short Wlds[4][4096];
    const int t = threadIdx.x;
    const int lane = t & 63, w = t >> 6;
    const int m = lane & 15, q = lane >> 4;

    const unsigned short* warr = (w == 0) ? F1h : (w == 1) ? F1l : (w == 2) ? F2h : F2l;
    #pragma unroll
    for (int i = 0; i < 8; ++i)
        dma16(warr + i * 512 + lane * 8, &Wlds[w][i * 512]);

    bf16x8 sh[2][2], sl[2][2], ph[2][2], pl[2][2];
    #pragma unroll
    for (int s = 0; s < 2; ++s) {
        int n = n0 + w * 32 + s * 16 + m;
        const float* fp = feat + (size_t)n * D;
        const float* hp = h_nb + (size_t)n * D;
        #pragma unroll
        for (int kb = 0; kb < 2; ++kb) {
            int d0 = kb * 32 + q * 8;
            float4 f0 = make_float4(0.f, 0.f, 0.f, 0.f), f1 = f0, h0 = f0, h1 = f0;
            if (n < N) {
                f0 = *(const float4*)(fp + d0); f1 = *(const float4*)(fp + d0 + 4);
                h0 = *(const float4*)(hp + d0); h1 = *(const float4*)(hp + d0 + 4);
            }
            float fv[8] = {f0.x, f0.y, f0.z, f0.w, f1.x, f1.y, f1.z, f1.w};
            float hv[8] = {h0.x, h0.y, h0.z, h0.w, h1.x, h1.y, h1.z, h1.w};
            bf16x8 a, b, c2, d2;
            #pragma unroll
            for (int j = 0; j < 8; ++j) {
                float xs = fv[j] + hv[j];
                float xp = fv[j] * hv[j];
                unsigned short hs = f2bf(xs);
                unsigned short hp2 = f2bf(xp);
                a[j]  = (short)hs;
                b[j]  = (short)f2bf(xs - bf2f(hs));
                c2[j] = (short)hp2;
                d2[j] = (short)f2bf(xp - bf2f(hp2));
            }
            sh[s][kb] = a; sl[s][kb] = b; ph[s][kb] = c2; pl[s][kb] = d2;
        }
    }
    __syncthreads();

    f32x4 a1[4][2], a2[4][2];
    #pragma unroll
    for (int c = 0; c < 4; ++c)
        #pragma unroll
        for (int s = 0; s < 2; ++s) {
            a1[c][s] = (f32x4){0.f, 0.f, 0.f, 0.f};
            a2[c][s] = (f32x4){0.f, 0.f, 0.f, 0.f};
        }
    #pragma unroll
    for (int c = 0; c < 4; ++c) {
        bf16x8 b1h[2], b1l[2], b2h[2], b2l[2];
        #pragma unroll
        for (int kb = 0; kb < 2; ++kb) {
            int o = (c * 2 + kb) * 512 + lane * 8;
            b1h[kb] = *(const bf16x8*)&Wlds[0][o];
            b1l[kb] = *(const bf16x8*)&Wlds[1][o];
            b2h[kb] = *(const bf16x8*)&Wlds[2][o];
            b2l[kb] = *(const bf16x8*)&Wlds[3][o];
        }
        #pragma unroll
        for (int kb = 0; kb < 2; ++kb)
            #pragma unroll
            for (int s = 0; s < 2; ++s) {
                a1[c][s] = __builtin_amdgcn_mfma_f32_16x16x32_bf16(sh[s][kb], b1h[kb], a1[c][s], 0, 0, 0);
                a1[c][s] = __builtin_amdgcn_mfma_f32_16x16x32_bf16(sl[s][kb], b1h[kb], a1[c][s], 0, 0, 0);
                a1[c][s] = __builtin_amdgcn_mfma_f32_16x16x32_bf16(sh[s][kb], b1l[kb], a1[c][s], 0, 0, 0);
                a2[c][s] = __builtin_amdgcn_mfma_f32_16x16x32_bf16(ph[s][kb], b2h[kb], a2[c][s], 0, 0, 0);
                a2[c][s] = __builtin_amdgcn_mfma_f32_16x16x32_bf16(pl[s][kb], b2h[kb], a2[c][s], 0, 0, 0);
                a2[c][s] = __builtin_amdgcn_mfma_f32_16x16x32_bf16(ph[s][kb], b2l[kb], a2[c][s], 0, 0, 0);
            }
    }

    #pragma unroll
    for (int s = 0; s < 2; ++s)
        #pragma unroll
        for (int i = 0; i < 4; ++i) {
            int n = n0 + w * 32 + s * 16 + q * 4 + i;
            if (n < N) {
                #pragma unroll
                for (int c = 0; c < 4; ++c) {
                    float o1 = a1[c][s][i];
                    float o2 = a2[c][s][i];
                    o1 = (o1 > 0.f) ? o1 : 0.01f * o1;
                    o2 = (o2 > 0.f) ? o2 : 0.01f * o2;
                    out[(size_t)n * D + c * 16 + m] = o1 + o2;
                }
            }
        }
}

extern "C" void kernel_launch(void* const* d_in, const int* in_sizes, int n_in,
                              void* d_out, int out_size, void* d_ws, size_t ws_size,
                              hipStream_t stream) {
    const float* feat  = (const float*)d_in[0];
    const float* relW  = (const float*)d_in[1];
    const float* relE  = (const float*)d_in[2];
    const float* W1    = (const float*)d_in[3];
    const float* W2    = (const float*)d_in[4];
    const int*   src   = (const int*)d_in[5];
    const int*   dst   = (const int*)d_in[6];
    const int*   etype = (const int*)d_in[7];
    float* out = (float*)d_out;

    const int N = in_sizes[0] / D;
    const int R = in_sizes[2] / D;
    const int E = in_sizes[5];

    char* w = (char*)d_ws;
    size_t off = 0;
    auto alloc = [&](size_t bytes) -> void* {
        void* p = w + off;
        off = (off + bytes + 255) & ~(size_t)255;
        return p;
    };
    unsigned short* varr = (unsigned short*)alloc((size_t)N * R * D * sizeof(unsigned short));
    float* h_nb   = (float*)alloc((size_t)N * D * sizeof(float));
    int* offsets  = (int*)alloc((size_t)(N + 1) * sizeof(int));
    int* tscan    = (int*)alloc((size_t)N * sizeof(int));
    int* cursor   = (int*)alloc((size_t)N * sizeof(int));
    int* deg      = (int*)alloc((size_t)N * sizeof(int));
    int* bsum     = (int*)alloc(2048 * sizeof(int));
    int* bofs     = (int*)alloc(2048 * sizeof(int));
    int* spack    = (int*)alloc((size_t)E * sizeof(int));
    size_t wfrag = (size_t)R * 4 * 2 * 64 * 8;
    unsigned short* B1h = (unsigned short*)alloc(wfrag * sizeof(unsigned short));
    unsigned short* B1l = (unsigned short*)alloc(wfrag * sizeof(unsigned short));
    unsigned short* B2h = (unsigned short*)alloc(wfrag * sizeof(unsigned short));
    unsigned short* B2l = (unsigned short*)alloc(wfrag * sizeof(unsigned short));
    unsigned short* F1h = (unsigned short*)alloc(4096 * sizeof(unsigned short));
    unsigned short* F1l = (unsigned short*)alloc(4096 * sizeof(unsigned short));
    unsigned short* F2h = (unsigned short*)alloc(4096 * sizeof(unsigned short));
    unsigned short* F2l = (unsigned short*)alloc(4096 * sizeof(unsigned short));
    (void)ws_size; (void)n_in; (void)out_size;

    const int NB = (N + 1023) / 1024;

    k_wsplit<<<(2 * R * 512 + 255) / 256, 256, 0, stream>>>(relW, B1h, B1l, B2h, B2l, R);
    k_wsplit2<<<4, 256, 0, stream>>>(W1, W2, F1h, F1l, F2h, F2l);
    hipMemsetAsync(deg, 0, (size_t)N * sizeof(int), stream);
    k_hist<<<(E + 255) / 256, 256, 0, stream>>>(dst, deg, E);
    k_scan1<<<NB, 1024, 0, stream>>>(deg, tscan, bsum, N);
    k_scan2<<<1, 1024, 0, stream>>>(bsum, bofs, NB);
    k_scan3<<<(N + 1 + 255) / 256, 256, 0, stream>>>(tscan, bofs, offsets, cursor, N);
    k_scatter<<<(E + 255) / 256, 256, 0, stream>>>(src, dst, etype, cursor, spack, E);
    k_projv<<<(N + 127) / 128, 256, 0, stream>>>(feat, B1h, B1l, B2h, B2l, relE, varr, N, R);
    k_fused2<<<(N + 3) / 4, 256, 0, stream>>>(varr, feat, offsets, spack, h_nb, N, R);
    k_final<<<(N + 127) / 128, 256, 0, stream>>>(feat, h_nb, F1h, F1l, F2h, F2l, out, N);
}

// Round 2
// 443.431 us; speedup vs baseline: 1.0500x; 1.0500x over previous
//
#include <hip/hip_runtime.h>
#include <math.h>

#define D 64

typedef __attribute__((ext_vector_type(8))) short bf16x8;
typedef __attribute__((ext_vector_type(4))) float f32x4;

static __device__ __forceinline__ unsigned short f2bf(float f) {
    unsigned int u = __float_as_uint(f);
    unsigned int r = (u + 0x7FFFu + ((u >> 16) & 1u)) >> 16;  // RNE
    return (unsigned short)r;
}
static __device__ __forceinline__ float bf2f(unsigned short h) {
    return __uint_as_float(((unsigned int)h) << 16);
}

#if defined(__has_builtin)
#if __has_builtin(__builtin_amdgcn_cvt_pk_bf16_f32)
#define HAVE_PK_BF16 1
#endif
#endif

static __device__ __forceinline__ unsigned int pk2bf(float a, float b) {
#ifdef HAVE_PK_BF16
    auto v = __builtin_amdgcn_cvt_pk_bf16_f32(a, b);   // low=a, high=b
    return *(unsigned int*)&v;
#else
    return (unsigned int)f2bf(a) | ((unsigned int)f2bf(b) << 16);
#endif
}

// tanh(x) = 1 - 2/(e^{2x}+1); inf-safe at extremes (no clamp needed)
static __device__ __forceinline__ float fast_tanh(float x) {
    float e = __expf(2.f * x);
    float r = __builtin_amdgcn_rcpf(e + 1.f);
    return 1.f - 2.f * r;
}

typedef __attribute__((address_space(1))) const unsigned int as1_uint;
typedef __attribute__((address_space(3))) unsigned int as3_uint;
static __device__ __forceinline__ void dma16(const void* g, void* l) {
    // async global->LDS, 16B/lane; LDS dest = uniform base + lane*16
    __builtin_amdgcn_global_load_lds((as1_uint*)g, (as3_uint*)l, 16, 0, 0);
}

// ---------------- pre-split W into MFMA B-fragment-ordered hi/lo bf16 arrays.
// B1 (GEMM1, P=feat@W):   element W[r][d=kb*32+q*8+j][o=c*16+m]
// B2 (GEMM2, V=u@W^T):    element W[r][d=c*16+m][o=kb*32+q*8+j]
// layout: [r][c][kb][lane=q*16+m][j]  -> chunk (r, c*2+kb) = 64 lanes x 16B
__global__ __launch_bounds__(256) void k_wsplit(const float* __restrict__ W,
                                                unsigned short* __restrict__ B1h,
                                                unsigned short* __restrict__ B1l,
                                                unsigned short* __restrict__ B2h,
                                                unsigned short* __restrict__ B2l,
                                                int R) {
    int idx = blockIdx.x * 256 + threadIdx.x;
    int per_g = R * 512;
    if (idx >= 2 * per_g) return;
    int g = idx / per_g;
    int rest = idx % per_g;
    int r = rest >> 9;
    int rest2 = rest & 511;
    int c = rest2 >> 7;
    int kb = (rest2 >> 6) & 1;
    int lane = rest2 & 63;
    int m = lane & 15, q = lane >> 4;
    bf16x8 hv, lv;
    #pragma unroll
    for (int j = 0; j < 8; ++j) {
        float v;
        if (g == 0) v = W[(size_t)r * 4096 + (kb * 32 + q * 8 + j) * 64 + (c * 16 + m)];
        else        v = W[(size_t)r * 4096 + (c * 16 + m) * 64 + (kb * 32 + q * 8 + j)];
        unsigned short h = f2bf(v);
        hv[j] = (short)h;
        lv[j] = (short)f2bf(v - bf2f(h));
    }
    size_t off = ((((size_t)r * 4 + c) * 2 + kb) * 64 + lane) * 8;
    unsigned short* ph = (g == 0) ? B1h : B2h;
    unsigned short* pl = (g == 0) ? B1l : B2l;
    *(bf16x8*)&ph[off] = hv;
    *(bf16x8*)&pl[off] = lv;
}

// ---------------- pre-split W1/W2 (for k_final): out = x @ Wk^T.
__global__ __launch_bounds__(256) void k_wsplit2(const float* __restrict__ W1,
                                                 const float* __restrict__ W2,
                                                 unsigned short* __restrict__ F1h,
                                                 unsigned short* __restrict__ F1l,
                                                 unsigned short* __restrict__ F2h,
                                                 unsigned short* __restrict__ F2l) {
    int idx = blockIdx.x * 256 + threadIdx.x;
    if (idx >= 1024) return;
    int g = idx >> 9;
    int rest2 = idx & 511;
    int c = rest2 >> 7;
    int kb = (rest2 >> 6) & 1;
    int lane = rest2 & 63;
    int m = lane & 15, q = lane >> 4;
    const float* W = g ? W2 : W1;
    bf16x8 hv, lv;
    #pragma unroll
    for (int j = 0; j < 8; ++j) {
        float v = W[(c * 16 + m) * 64 + kb * 32 + q * 8 + j];
        unsigned short h = f2bf(v);
        hv[j] = (short)h;
        lv[j] = (short)f2bf(v - bf2f(h));
    }
    size_t off = (((size_t)c * 2 + kb) * 64 + lane) * 8;
    unsigned short* ph = g ? F2h : F1h;
    unsigned short* pl = g ? F2l : F1l;
    *(bf16x8*)&ph[off] = hv;
    *(bf16x8*)&pl[off] = lv;
}

// ---------------- fused proj+V, r-quartered grid to kill the scheduling tail.
// Block = (tile of 128 nodes) x (4 relations). Grid = ceil(N/128) * R/4 = 3128.
// Quantum ~= c/4 ~= 7.6us -> greedy HW dispatch balances 3128 quanta over
// 1024 resident slots; makespan ~= ideal (92us) + 1 quantum, vs 4c=121us for
// the 782-block grid (14 straggler blocks cost a full extra c).
// LDS: 32KB B (rows 0-15 = B1(r), rows 16-31 = B2(r)) + 8KB per-s Us = 40KB
// -> 4 blocks/CU. GEMM1 s-hoisted (B-frags read once); epi+GEMM2+store per-s.
__global__ __launch_bounds__(256, 4) void k_projv(const float* __restrict__ feat,
                                                  const unsigned short* __restrict__ B1h,
                                                  const unsigned short* __restrict__ B1l,
                                                  const unsigned short* __restrict__ B2h,
                                                  const unsigned short* __restrict__ B2l,
                                                  const float* __restrict__ emb,
                                                  unsigned short* __restrict__ V,
                                                  int N, int R, int nrq) {
    const int tile = blockIdx.x / nrq;
    const int rq   = blockIdx.x % nrq;
    const int rbase = rq * 4;
    const int rcnt  = (R - rbase < 4) ? (R - rbase) : 4;
    const int n0 = tile * 128;
    __shared__ __align__(16) unsigned short Bbuf[32][512];   // 32 KB
    __shared__ __align__(16) unsigned short Us[4][1024];     // 8 KB (per-s, wave-private)
    const int t = threadIdx.x;
    const int lane = t & 63, w = t >> 6;
    const int m = lane & 15, q = lane >> 4;

    // ---- A-frags direct from global, split hi/lo in-register
    bf16x8 ah[2][2], al[2][2];
    #pragma unroll
    for (int s = 0; s < 2; ++s) {
        int n = n0 + w * 32 + s * 16 + m;
        const float* rowp = feat + (size_t)n * D;
        #pragma unroll
        for (int kb = 0; kb < 2; ++kb) {
            int d0 = kb * 32 + q * 8;
            float4 v0 = make_float4(0.f, 0.f, 0.f, 0.f), v1 = v0;
            if (n < N) { v0 = *(const float4*)(rowp + d0); v1 = *(const float4*)(rowp + d0 + 4); }
            float vals[8] = {v0.x, v0.y, v0.z, v0.w, v1.x, v1.y, v1.z, v1.w};
            bf16x8 hv, lv;
            #pragma unroll
            for (int j = 0; j < 8; ++j) {
                unsigned short h = f2bf(vals[j]);
                hv[j] = (short)h;
                lv[j] = (short)f2bf(vals[j] - bf2f(h));
            }
            ah[s][kb] = hv; al[s][kb] = lv;
        }
    }

    // stage one 16KB half (B1 -> rows 0-15, or B2 -> rows 16-31), all 4 waves:
    // wave w takes 4 of the 16 1KB chunks.
    auto stage_half = [&](int r, int half) {
        const unsigned short* arr = half ? ((w < 2) ? B2h : B2l)
                                         : ((w < 2) ? B1h : B1l);
        const unsigned short* gp = arr + (size_t)r * 4096 + (size_t)(w & 1) * 2048 + lane * 8;
        unsigned short* lp = &Bbuf[half * 16 + (w >> 1) * 8 + (w & 1) * 4][0];
        #pragma unroll
        for (int i = 0; i < 4; ++i)
            dma16(gp + i * 512, lp + i * 512);
    };

    stage_half(rbase, 0);
    stage_half(rbase, 1);
    __syncthreads();

    for (int rr = 0; rr < rcnt; ++rr) {
        const int r = rbase + rr;
        float em[4];
        #pragma unroll
        for (int c = 0; c < 4; ++c) em[c] = emb[r * 64 + c * 16 + m];

        // ---------- GEMM1 (both s): P = feat @ W_r (3-term split), B-frags hoisted
        f32x4 acc[4][2];
        #pragma unroll
        for (int c = 0; c < 4; ++c)
            #pragma unroll
            for (int s = 0; s < 2; ++s) acc[c][s] = (f32x4){0.f, 0.f, 0.f, 0.f};
        #pragma unroll
        for (int c = 0; c < 4; ++c) {
            bf16x8 bh[2], bl[2];
            #pragma unroll
            for (int kb = 0; kb < 2; ++kb) {
                bh[kb] = *(const bf16x8*)&Bbuf[c * 2 + kb][lane * 8];
                bl[kb] = *(const bf16x8*)&Bbuf[8 + c * 2 + kb][lane * 8];
            }
            #pragma unroll
            for (int s = 0; s < 2; ++s)
                #pragma unroll
                for (int kb = 0; kb < 2; ++kb) {
                    acc[c][s] = __builtin_amdgcn_mfma_f32_16x16x32_bf16(ah[s][kb], bh[kb], acc[c][s], 0, 0, 0);
                    acc[c][s] = __builtin_amdgcn_mfma_f32_16x16x32_bf16(al[s][kb], bh[kb], acc[c][s], 0, 0, 0);
                    acc[c][s] = __builtin_amdgcn_mfma_f32_16x16x32_bf16(ah[s][kb], bl[kb], acc[c][s], 0, 0, 0);
                }
        }

        __syncthreads();                         // rows 0-15 consumed
        if (rr + 1 < rcnt) stage_half(r + 1, 0); // B1(r+1) DMA overlaps epi+GEMM2

        // ---------- per-s: epilogue -> Us, GEMM2, store (Us reused across s;
        // same-wave LDS ops are in-order so s=1 writes can't pass s=0 reads)
        #pragma unroll
        for (int s = 0; s < 2; ++s) {
            #pragma unroll
            for (int c = 0; c < 4; ++c) {
                int o = c * 16 + m;
                int kb2 = o >> 5;
                int q2 = (o >> 3) & 3;
                int j = o & 7;
                int Fb = kb2 * 64 + q2 * 16 + q * 4;
                #pragma unroll
                for (int i = 0; i < 4; i += 2) {
                    float t0 = fast_tanh(acc[c][s][i] + em[c]);
                    float t1 = fast_tanh(acc[c][s][i + 1] + em[c]);
                    unsigned int pk = pk2bf(t0, t1);
                    Us[w][((Fb + i) ^ q2) * 8 + j]     = (unsigned short)(pk & 0xFFFF);
                    Us[w][((Fb + i + 1) ^ q2) * 8 + j] = (unsigned short)(pk >> 16);
                }
            }

            bf16x8 ua[2];
            #pragma unroll
            for (int kb = 0; kb < 2; ++kb) {
                int F = kb * 64 + lane;
                ua[kb] = *(const bf16x8*)&Us[w][(F ^ (lane >> 4)) * 8];
            }
            f32x4 acc2[4];
            #pragma unroll
            for (int c = 0; c < 4; ++c) acc2[c] = (f32x4){0.f, 0.f, 0.f, 0.f};
            #pragma unroll
            for (int c = 0; c < 4; ++c) {
                bf16x8 bh[2], bl[2];
                #pragma unroll
                for (int kb = 0; kb < 2; ++kb) {
                    bh[kb] = *(const bf16x8*)&Bbuf[16 + c * 2 + kb][lane * 8];
                    bl[kb] = *(const bf16x8*)&Bbuf[24 + c * 2 + kb][lane * 8];
                }
                #pragma unroll
                for (int kb = 0; kb < 2; ++kb) {
                    acc2[c] = __builtin_amdgcn_mfma_f32_16x16x32_bf16(ua[kb], bh[kb], acc2[c], 0, 0, 0);
                    acc2[c] = __builtin_amdgcn_mfma_f32_16x16x32_bf16(ua[kb], bl[kb], acc2[c], 0, 0, 0);
                }
            }

            #pragma unroll
            for (int i = 0; i < 4; ++i) {
                int n = n0 + w * 32 + s * 16 + q * 4 + i;
                if (n < N) {
                    uint2 pv;
                    pv.x = pk2bf(acc2[0][i], acc2[1][i]);
                    pv.y = pk2bf(acc2[2][i], acc2[3][i]);
                    *(uint2*)&V[((size_t)n * R + r) * 64 + m * 4] = pv;
                }
            }
        }

        __syncthreads();                         // rows 16-31 consumed; half-0 DMA drained
        if (rr + 1 < rcnt) stage_half(r + 1, 1); // B2(r+1) DMA overlaps next GEMM1
    }
}

// ---------------- histogram of dst
__global__ __launch_bounds__(256) void k_hist(const int* __restrict__ dst, int* __restrict__ deg, int E) {
    int e = blockIdx.x * 256 + threadIdx.x;
    if (e < E) atomicAdd(&deg[dst[e]], 1);
}

// ---------------- scan step 1
__global__ __launch_bounds__(1024) void k_scan1(const int* __restrict__ deg, int* __restrict__ tscan,
                                                int* __restrict__ bsum, int N) {
    __shared__ int s[1024];
    const int t = threadIdx.x;
    const int i = blockIdx.x * 1024 + t;
    int v = (i < N) ? deg[i] : 0;
    s[t] = v;
    __syncthreads();
    for (int off = 1; off < 1024; off <<= 1) {
        int tmp = (t >= off) ? s[t - off] : 0;
        __syncthreads();
        s[t] += tmp;
        __syncthreads();
    }
    if (i < N) tscan[i] = s[t];
    if (t == 1023) bsum[blockIdx.x] = s[1023];
}

// ---------------- scan step 2
__global__ __launch_bounds__(1024) void k_scan2(const int* __restrict__ bsum, int* __restrict__ bofs, int NB) {
    __shared__ int s[1024];
    const int t = threadIdx.x;
    int carry = 0;
    for (int b0 = 0; b0 < NB; b0 += 1024) {
        int i = b0 + t;
        int v = (i < NB) ? bsum[i] : 0;
        s[t] = v;
        __syncthreads();
        for (int off = 1; off < 1024; off <<= 1) {
            int tmp = (t >= off) ? s[t - off] : 0;
            __syncthreads();
            s[t] += tmp;
            __syncthreads();
        }
        if (i < NB) bofs[i] = carry + s[t] - v;
        int tot = s[1023];
        __syncthreads();
        carry += tot;
    }
}

// ---------------- scan step 3
__global__ __launch_bounds__(256) void k_scan3(const int* __restrict__ tscan, const int* __restrict__ bofs,
                                               int* __restrict__ offsets, int* __restrict__ cursor, int N) {
    int i = blockIdx.x * 256 + threadIdx.x;
    if (i <= N) {
        int v = (i == 0) ? 0 : (tscan[i - 1] + bofs[(i - 1) >> 10]);
        offsets[i] = v;
        if (i < N) cursor[i] = v;
    }
}

// ---------------- scatter edges into dst-sorted order
__global__ __launch_bounds__(256) void k_scatter(const int* __restrict__ src, const int* __restrict__ dst,
                                                 const int* __restrict__ etype, int* __restrict__ cursor,
                                                 int* __restrict__ spack, int E) {
    int e = blockIdx.x * 256 + threadIdx.x;
    if (e < E) {
        int d = dst[e];
        int p = atomicAdd(&cursor[d], 1);
        spack[p] = src[e] | (etype[e] << 20);
    }
}

// ---------------- fused att + softmax + aggregation: 4 edges per wave-iteration.
__global__ __launch_bounds__(256) void k_fused2(const unsigned short* __restrict__ V,
                                                const float* __restrict__ feat,
                                                const int* __restrict__ offsets,
                                                const int* __restrict__ spack,
                                                float* __restrict__ h_nb,
                                                int N, int R) {
    const int lane = threadIdx.x & 63;
    const int wav  = threadIdx.x >> 6;
    const int g    = lane >> 4;
    const int k    = lane & 15;
    const int n = blockIdx.x * 4 + wav;
    __shared__ float vlds[4][1024];
    if (n >= N) return;

    const unsigned int* v32 = (const unsigned int*)(V + (size_t)n * R * D);
    #pragma unroll
    for (int j = 0; j < 8; ++j) {
        int uidx = j * 64 + lane;
        unsigned int u = v32[uidx];
        int r  = uidx >> 5;
        int k2 = uidx & 31;
        int mm = k2 >> 1;
        int cc = (k2 & 1) * 2;
        int o  = cc * 16 + mm;
        vlds[wav][r * 64 + o]      = bf2f((unsigned short)(u & 0xFFFF));
        vlds[wav][r * 64 + o + 16] = bf2f((unsigned short)(u >> 16));
    }

    const int beg = offsets[n], end = offsets[n + 1];
    float m = -INFINITY, l = 0.f;
    float4 acc = make_float4(0.f, 0.f, 0.f, 0.f);

    if (beg < end) {
        int e = beg + g;
        bool ok = e < end;
        int pk = spack[ok ? e : (end - 1)];
        float4 f = *(const float4*)&feat[(size_t)(pk & 0xFFFFF) * D + k * 4];

        for (int i = beg; i < end; i += 4) {
            const int   et  = pk >> 20;
            const float4 fc = f;
            const bool  okc = ok;
            int e2 = i + 4 + g;
            ok = e2 < end;
            pk = spack[ok ? e2 : (end - 1)];
            f = *(const float4*)&feat[(size_t)(pk & 0xFFFFF) * D + k * 4];

            float4 v = *(const float4*)&vlds[wav][et * 64 + k * 4];
            float p = fc.x * v.x + fc.y * v.y + fc.z * v.z + fc.w * v.w;
            p += __shfl_xor(p, 1, 64);
            p += __shfl_xor(p, 2, 64);
            p += __shfl_xor(p, 4, 64);
            p += __shfl_xor(p, 8, 64);
            p = okc ? p : -INFINITY;
            float tmx = fmaxf(p, __shfl_xor(p, 16, 64));
            float nm4 = fmaxf(tmx, __shfl_xor(tmx, 32, 64));
            float nm  = fmaxf(m, nm4);
            float scale = __expf(m - nm);
            float wg    = __expf(p - nm);
            float sw = wg + __shfl_xor(wg, 16, 64);
            sw += __shfl_xor(sw, 32, 64);
            l = l * scale + sw;
            acc.x = acc.x * scale + wg * fc.x;
            acc.y = acc.y * scale + wg * fc.y;
            acc.z = acc.z * scale + wg * fc.z;
            acc.w = acc.w * scale + wg * fc.w;
            m = nm;
        }
        acc.x += __shfl_xor(acc.x, 16, 64);
        acc.y += __shfl_xor(acc.y, 16, 64);
        acc.z += __shfl_xor(acc.z, 16, 64);
        acc.w += __shfl_xor(acc.w, 16, 64);
        acc.x += __shfl_xor(acc.x, 32, 64);
        acc.y += __shfl_xor(acc.y, 32, 64);
        acc.z += __shfl_xor(acc.z, 32, 64);
        acc.w += __shfl_xor(acc.w, 32, 64);
        float inv = 1.f / l;
        acc.x *= inv; acc.y *= inv; acc.z *= inv; acc.w *= inv;
    }
    if (lane < 16)
        *(float4*)&h_nb[(size_t)n * D + k * 4] = acc;
}

// ---------------- final via MFMA: out = lrelu((f+h)@W1^T) + lrelu((f*h)@W2^T)
__global__ __launch_bounds__(256, 2) void k_final(const float* __restrict__ feat,
                                                  const float* __restrict__ h_nb,
                                                  const unsigned short* __restrict__ F1h,
                                                  const unsigned short* __restrict__ F1l,
                                                  const unsigned short* __restrict__ F2h,
                                                  const unsigned short* __restrict__ F2l,
                                                  float* __restrict__ out, int N) {
    const int n0 = blockIdx.x * 128;
    __shared__ __align__(16) unsigned short Wlds[4][4096];
    const int t = threadIdx.x;
    const int lane = t & 63, w = t >> 6;
    const int m = lane & 15, q = lane >> 4;

    const unsigned short* warr = (w == 0) ? F1h : (w == 1) ? F1l : (w == 2) ? F2h : F2l;
    #pragma unroll
    for (int i = 0; i < 8; ++i)
        dma16(warr + i * 512 + lane * 8, &Wlds[w][i * 512]);

    bf16x8 sh[2][2], sl[2][2], ph[2][2], pl[2][2];
    #pragma unroll
    for (int s = 0; s < 2; ++s) {
        int n = n0 + w * 32 + s * 16 + m;
        const float* fp = feat + (size_t)n * D;
        const float* hp = h_nb + (size_t)n * D;
        #pragma unroll
        for (int kb = 0; kb < 2; ++kb) {
            int d0 = kb * 32 + q * 8;
            float4 f0 = make_float4(0.f, 0.f, 0.f, 0.f), f1 = f0, h0 = f0, h1 = f0;
            if (n < N) {
                f0 = *(const float4*)(fp + d0); f1 = *(const float4*)(fp + d0 + 4);
                h0 = *(const float4*)(hp + d0); h1 = *(const float4*)(hp + d0 + 4);
            }
            float fv[8] = {f0.x, f0.y, f0.z, f0.w, f1.x, f1.y, f1.z, f1.w};
            float hv[8] = {h0.x, h0.y, h0.z, h0.w, h1.x, h1.y, h1.z, h1.w};
            bf16x8 a, b, c2, d2;
            #pragma unroll
            for (int j = 0; j < 8; ++j) {
                float xs = fv[j] + hv[j];
                float xp = fv[j] * hv[j];
                unsigned short hs = f2bf(xs);
                unsigned short hp2 = f2bf(xp);
                a[j]  = (short)hs;
                b[j]  = (short)f2bf(xs - bf2f(hs));
                c2[j] = (short)hp2;
                d2[j] = (short)f2bf(xp - bf2f(hp2));
            }
            sh[s][kb] = a; sl[s][kb] = b; ph[s][kb] = c2; pl[s][kb] = d2;
        }
    }
    __syncthreads();

    f32x4 a1[4][2], a2[4][2];
    #pragma unroll
    for (int c = 0; c < 4; ++c)
        #pragma unroll
        for (int s = 0; s < 2; ++s) {
            a1[c][s] = (f32x4){0.f, 0.f, 0.f, 0.f};
            a2[c][s] = (f32x4){0.f, 0.f, 0.f, 0.f};
        }
    #pragma unroll
    for (int c = 0; c < 4; ++c) {
        bf16x8 b1h[2], b1l[2], b2h[2], b2l[2];
        #pragma unroll
        for (int kb = 0; kb < 2; ++kb) {
            int o = (c * 2 + kb) * 512 + lane * 8;
            b1h[kb] = *(const bf16x8*)&Wlds[0][o];
            b1l[kb] = *(const bf16x8*)&Wlds[1][o];
            b2h[kb] = *(const bf16x8*)&Wlds[2][o];
            b2l[kb] = *(const bf16x8*)&Wlds[3][o];
        }
        #pragma unroll
        for (int kb = 0; kb < 2; ++kb)
            #pragma unroll
            for (int s = 0; s < 2; ++s) {
                a1[c][s] = __builtin_amdgcn_mfma_f32_16x16x32_bf16(sh[s][kb], b1h[kb], a1[c][s], 0, 0, 0);
                a1[c][s] = __builtin_amdgcn_mfma_f32_16x16x32_bf16(sl[s][kb], b1h[kb], a1[c][s], 0, 0, 0);
                a1[c][s] = __builtin_amdgcn_mfma_f32_16x16x32_bf16(sh[s][kb], b1l[kb], a1[c][s], 0, 0, 0);
                a2[c][s] = __builtin_amdgcn_mfma_f32_16x16x32_bf16(ph[s][kb], b2h[kb], a2[c][s], 0, 0, 0);
                a2[c][s] = __builtin_amdgcn_mfma_f32_16x16x32_bf16(pl[s][kb], b2h[kb], a2[c][s], 0, 0, 0);
                a2[c][s] = __builtin_amdgcn_mfma_f32_16x16x32_bf16(ph[s][kb], b2l[kb], a2[c][s], 0, 0, 0);
            }
    }

    #pragma unroll
    for (int s = 0; s < 2; ++s)
        #pragma unroll
        for (int i = 0; i < 4; ++i) {
            int n = n0 + w * 32 + s * 16 + q * 4 + i;
            if (n < N) {
                #pragma unroll
                for (int c = 0; c < 4; ++c) {
                    float o1 = a1[c][s][i];
                    float o2 = a2[c][s][i];
                    o1 = (o1 > 0.f) ? o1 : 0.01f * o1;
                    o2 = (o2 > 0.f) ? o2 : 0.01f * o2;
                    out[(size_t)n * D + c * 16 + m] = o1 + o2;
                }
            }
        }
}

extern "C" void kernel_launch(void* const* d_in, const int* in_sizes, int n_in,
                              void* d_out, int out_size, void* d_ws, size_t ws_size,
                              hipStream_t stream) {
    const float* feat  = (const float*)d_in[0];
    const float* relW  = (const float*)d_in[1];
    const float* relE  = (const float*)d_in[2];
    const float* W1    = (const float*)d_in[3];
    const float* W2    = (const float*)d_in[4];
    const int*   src   = (const int*)d_in[5];
    const int*   dst   = (const int*)d_in[6];
    const int*   etype = (const int*)d_in[7];
    float* out = (float*)d_out;

    const int N = in_sizes[0] / D;
    const int R = in_sizes[2] / D;
    const int E = in_sizes[5];

    char* w = (char*)d_ws;
    size_t off = 0;
    auto alloc = [&](size_t bytes) -> void* {
        void* p = w + off;
        off = (off + bytes + 255) & ~(size_t)255;
        return p;
    };
    unsigned short* varr = (unsigned short*)alloc((size_t)N * R * D * sizeof(unsigned short));
    float* h_nb   = (float*)alloc((size_t)N * D * sizeof(float));
    int* offsets  = (int*)alloc((size_t)(N + 1) * sizeof(int));
    int* tscan    = (int*)alloc((size_t)N * sizeof(int));
    int* cursor   = (int*)alloc((size_t)N * sizeof(int));
    int* deg      = (int*)alloc((size_t)N * sizeof(int));
    int* bsum     = (int*)alloc(2048 * sizeof(int));
    int* bofs     = (int*)alloc(2048 * sizeof(int));
    int* spack    = (int*)alloc((size_t)E * sizeof(int));
    size_t wfrag = (size_t)R * 4 * 2 * 64 * 8;
    unsigned short* B1h = (unsigned short*)alloc(wfrag * sizeof(unsigned short));
    unsigned short* B1l = (unsigned short*)alloc(wfrag * sizeof(unsigned short));
    unsigned short* B2h = (unsigned short*)alloc(wfrag * sizeof(unsigned short));
    unsigned short* B2l = (unsigned short*)alloc(wfrag * sizeof(unsigned short));
    unsigned short* F1h = (unsigned short*)alloc(4096 * sizeof(unsigned short));
    unsigned short* F1l = (unsigned short*)alloc(4096 * sizeof(unsigned short));
    unsigned short* F2h = (unsigned short*)alloc(4096 * sizeof(unsigned short));
    unsigned short* F2l = (unsigned short*)alloc(4096 * sizeof(unsigned short));
    (void)ws_size; (void)n_in; (void)out_size;

    const int NB = (N + 1023) / 1024;
    const int nrq = (R + 3) / 4;                  // r-quarters per tile
    const int ntiles = (N + 127) / 128;

    k_wsplit<<<(2 * R * 512 + 255) / 256, 256, 0, stream>>>(relW, B1h, B1l, B2h, B2l, R);
    k_wsplit2<<<4, 256, 0, stream>>>(W1, W2, F1h, F1l, F2h, F2l);
    hipMemsetAsync(deg, 0, (size_t)N * sizeof(int), stream);
    k_hist<<<(E + 255) / 256, 256, 0, stream>>>(dst, deg, E);
    k_scan1<<<NB, 1024, 0, stream>>>(deg, tscan, bsum, N);
    k_scan2<<<1, 1024, 0, stream>>>(bsum, bofs, NB);
    k_scan3<<<(N + 1 + 255) / 256, 256, 0, stream>>>(tscan, bofs, offsets, cursor, N);
    k_scatter<<<(E + 255) / 256, 256, 0, stream>>>(src, dst, etype, cursor, spack, E);
    k_projv<<<ntiles * nrq, 256, 0, stream>>>(feat, B1h, B1l, B2h, B2l, relE, varr, N, R, nrq);
    k_fused2<<<(N + 3) / 4, 256, 0, stream>>>(varr, feat, offsets, spack, h_nb, N, R);
    k_final<<<(N + 127) / 128, 256, 0, stream>>>(feat, h_nb, F1h, F1l, F2h, F2l, out, N);
}

// Round 4
// 369.125 us; speedup vs baseline: 1.2614x; 1.2013x over previous
//
#include <hip/hip_runtime.h>
#include <math.h>

#define D 64

typedef __attribute__((ext_vector_type(8))) short bf16x8;
typedef __attribute__((ext_vector_type(4))) float f32x4;

static __device__ __forceinline__ unsigned short f2bf(float f) {
    unsigned int u = __float_as_uint(f);
    unsigned int r = (u + 0x7FFFu + ((u >> 16) & 1u)) >> 16;  // RNE
    return (unsigned short)r;
}
static __device__ __forceinline__ float bf2f(unsigned short h) {
    return __uint_as_float(((unsigned int)h) << 16);
}

#if defined(__has_builtin)
#if __has_builtin(__builtin_amdgcn_cvt_pk_bf16_f32)
#define HAVE_PK_BF16 1
#endif
#endif

static __device__ __forceinline__ unsigned int pk2bf(float a, float b) {
#ifdef HAVE_PK_BF16
    auto v = __builtin_amdgcn_cvt_pk_bf16_f32(a, b);   // low=a, high=b
    return *(unsigned int*)&v;
#else
    return (unsigned int)f2bf(a) | ((unsigned int)f2bf(b) << 16);
#endif
}

// tanh(x) = 1 - 2/(e^{2x}+1); inf-safe at extremes (no clamp needed)
static __device__ __forceinline__ float fast_tanh(float x) {
    float e = __expf(2.f * x);
    float r = __builtin_amdgcn_rcpf(e + 1.f);
    return 1.f - 2.f * r;
}

typedef __attribute__((address_space(1))) const unsigned int as1_uint;
typedef __attribute__((address_space(3))) unsigned int as3_uint;
static __device__ __forceinline__ void dma16(const void* g, void* l) {
    // async global->LDS, 16B/lane; LDS dest = uniform base + lane*16
    __builtin_amdgcn_global_load_lds((as1_uint*)g, (as3_uint*)l, 16, 0, 0);
}

// ---------------- pre-split W into MFMA B-fragment-ordered hi/lo bf16 arrays.
__global__ __launch_bounds__(256) void k_wsplit(const float* __restrict__ W,
                                                unsigned short* __restrict__ B1h,
                                                unsigned short* __restrict__ B1l,
                                                unsigned short* __restrict__ B2h,
                                                unsigned short* __restrict__ B2l,
                                                int R) {
    int idx = blockIdx.x * 256 + threadIdx.x;
    int per_g = R * 512;
    if (idx >= 2 * per_g) return;
    int g = idx / per_g;
    int rest = idx % per_g;
    int r = rest >> 9;
    int rest2 = rest & 511;
    int c = rest2 >> 7;
    int kb = (rest2 >> 6) & 1;
    int lane = rest2 & 63;
    int m = lane & 15, q = lane >> 4;
    bf16x8 hv, lv;
    #pragma unroll
    for (int j = 0; j < 8; ++j) {
        float v;
        if (g == 0) v = W[(size_t)r * 4096 + (kb * 32 + q * 8 + j) * 64 + (c * 16 + m)];
        else        v = W[(size_t)r * 4096 + (c * 16 + m) * 64 + (kb * 32 + q * 8 + j)];
        unsigned short h = f2bf(v);
        hv[j] = (short)h;
        lv[j] = (short)f2bf(v - bf2f(h));
    }
    size_t off = ((((size_t)r * 4 + c) * 2 + kb) * 64 + lane) * 8;
    unsigned short* ph = (g == 0) ? B1h : B2h;
    unsigned short* pl = (g == 0) ? B1l : B2l;
    *(bf16x8*)&ph[off] = hv;
    *(bf16x8*)&pl[off] = lv;
}

// ---------------- pre-split W1/W2 (for k_final): out = x @ Wk^T.
__global__ __launch_bounds__(256) void k_wsplit2(const float* __restrict__ W1,
                                                 const float* __restrict__ W2,
                                                 unsigned short* __restrict__ F1h,
                                                 unsigned short* __restrict__ F1l,
                                                 unsigned short* __restrict__ F2h,
                                                 unsigned short* __restrict__ F2l) {
    int idx = blockIdx.x * 256 + threadIdx.x;
    if (idx >= 1024) return;
    int g = idx >> 9;
    int rest2 = idx & 511;
    int c = rest2 >> 7;
    int kb = (rest2 >> 6) & 1;
    int lane = rest2 & 63;
    int m = lane & 15, q = lane >> 4;
    const float* W = g ? W2 : W1;
    bf16x8 hv, lv;
    #pragma unroll
    for (int j = 0; j < 8; ++j) {
        float v = W[(c * 16 + m) * 64 + kb * 32 + q * 8 + j];
        unsigned short h = f2bf(v);
        hv[j] = (short)h;
        lv[j] = (short)f2bf(v - bf2f(h));
    }
    size_t off = (((size_t)c * 2 + kb) * 64 + lane) * 8;
    unsigned short* ph = g ? F2h : F1h;
    unsigned short* pl = g ? F2l : F1l;
    *(bf16x8*)&ph[off] = hv;
    *(bf16x8*)&pl[off] = lv;
}

// ================= CSR build via deterministic two-level bucket sort =========
// bucket = dst >> 7 (128 nodes per bucket). NBUK = ceil(N/128) <= 1024.
// NB3 = 256 edge chunks. cnt[(b<<8)|blk] -> exclusive scan -> csc gives each
// (bucket, block) a deterministic write base: NO global atomics anywhere.
#define NB3 256

// ---- pass 1: per-chunk bucket histogram (LDS), write cnt[bucket][chunk]
__global__ __launch_bounds__(256) void k_bcount(const int* __restrict__ dst,
                                                int* __restrict__ cnt,
                                                int E, int CH, int NBUK) {
    __shared__ int h[1024];
    const int t = threadIdx.x, blk = blockIdx.x;
    for (int b = t; b < NBUK; b += 256) h[b] = 0;
    __syncthreads();
    const int s0 = blk * CH, s1 = min(E, s0 + CH);
    for (int e = s0 + t; e < s1; e += 256)
        atomicAdd(&h[dst[e] >> 7], 1);
    __syncthreads();
    for (int b = t; b < NBUK; b += 256)
        cnt[(b << 8) | blk] = h[b];
}

// ---- pass 2: scatter edges into bucket-grouped ebuf (deterministic bases)
// payload pack: src[0:20) | etype[20:25) | (dst&127)[25:32)
__global__ __launch_bounds__(256) void k_bscatter(const int* __restrict__ src,
                                                  const int* __restrict__ dst,
                                                  const int* __restrict__ etype,
                                                  const int* __restrict__ csc,
                                                  int* __restrict__ ebuf,
                                                  int E, int CH, int NBUK) {
    __shared__ int cur[1024];
    const int t = threadIdx.x, blk = blockIdx.x;
    for (int b = t; b < NBUK; b += 256) cur[b] = csc[(b << 8) | blk];
    __syncthreads();
    const int s0 = blk * CH, s1 = min(E, s0 + CH);
    for (int e = s0 + t; e < s1; e += 256) {
        int d = dst[e];
        int b = d >> 7;
        int pos = atomicAdd(&cur[b], 1);
        unsigned int pk = (unsigned int)src[e] | ((unsigned int)etype[e] << 20)
                        | ((unsigned int)(d & 127) << 25);
        ebuf[pos] = (int)pk;
    }
}

// ---- pass 3: one block per bucket: per-node degree + prefix (LDS) -> global
// CSR offsets directly (bucket base + intra-bucket prefix), then LDS-cursor
// scatter of payloads into the bucket's contiguous window (L2-hot).
__global__ __launch_bounds__(256) void k_bcsr(const int* __restrict__ ebuf,
                                              const int* __restrict__ csc,
                                              int* __restrict__ offsets,
                                              int* __restrict__ spack,
                                              int N, int E, int NBUK) {
    __shared__ int sdeg[128], sincl[128], scur[128];
    const int t = threadIdx.x, b = blockIdx.x;
    const int s0 = csc[b << 8];
    const int s1 = csc[(b + 1) << 8];
    if (t < 128) { sdeg[t] = 0; }
    __syncthreads();
    for (int e = s0 + t; e < s1; e += 256)
        atomicAdd(&sdeg[((unsigned int)ebuf[e]) >> 25], 1);
    __syncthreads();
    if (t < 128) sincl[t] = sdeg[t];
    __syncthreads();
    for (int off = 1; off < 128; off <<= 1) {
        int v = 0;
        if (t < 128 && t >= off) v = sincl[t - off];
        __syncthreads();
        if (t < 128) sincl[t] += v;
        __syncthreads();
    }
    if (t < 128) {
        int excl = sincl[t] - sdeg[t];
        scur[t] = s0 + excl;
        int n = (b << 7) + t;
        if (n < N) offsets[n] = s0 + excl;
    }
    if (b == NBUK - 1 && t == 0) offsets[N] = E;
    __syncthreads();
    for (int e = s0 + t; e < s1; e += 256) {
        unsigned int pk = (unsigned int)ebuf[e];
        int i = pk >> 25;
        int p = atomicAdd(&scur[i], 1);
        spack[p] = (int)(pk & 0x01FFFFFFu);
    }
}

// ---------------- scan step 1 (generic length)
__global__ __launch_bounds__(1024) void k_scan1(const int* __restrict__ deg, int* __restrict__ tscan,
                                                int* __restrict__ bsum, int N) {
    __shared__ int s[1024];
    const int t = threadIdx.x;
    const int i = blockIdx.x * 1024 + t;
    int v = (i < N) ? deg[i] : 0;
    s[t] = v;
    __syncthreads();
    for (int off = 1; off < 1024; off <<= 1) {
        int tmp = (t >= off) ? s[t - off] : 0;
        __syncthreads();
        s[t] += tmp;
        __syncthreads();
    }
    if (i < N) tscan[i] = s[t];
    if (t == 1023) bsum[blockIdx.x] = s[1023];
}

// ---------------- scan step 2
__global__ __launch_bounds__(1024) void k_scan2(const int* __restrict__ bsum, int* __restrict__ bofs, int NB) {
    __shared__ int s[1024];
    const int t = threadIdx.x;
    int carry = 0;
    for (int b0 = 0; b0 < NB; b0 += 1024) {
        int i = b0 + t;
        int v = (i < NB) ? bsum[i] : 0;
        s[t] = v;
        __syncthreads();
        for (int off = 1; off < 1024; off <<= 1) {
            int tmp = (t >= off) ? s[t - off] : 0;
            __syncthreads();
            s[t] += tmp;
            __syncthreads();
        }
        if (i < NB) bofs[i] = carry + s[t] - v;
        int tot = s[1023];
        __syncthreads();
        carry += tot;
    }
}

// ---------------- scan step 3: exclusive scan output (length L+1), no cursor
__global__ __launch_bounds__(256) void k_scanout(const int* __restrict__ tscan, const int* __restrict__ bofs,
                                                 int* __restrict__ outv, int L) {
    int i = blockIdx.x * 256 + threadIdx.x;
    if (i <= L) {
        outv[i] = (i == 0) ? 0 : (tscan[i - 1] + bofs[(i - 1) >> 10]);
    }
}

// ---------------- fused proj+V, r-quartered grid (tile x r-quarter blocks).
__global__ __launch_bounds__(256, 4) void k_projv(const float* __restrict__ feat,
                                                  const unsigned short* __restrict__ B1h,
                                                  const unsigned short* __restrict__ B1l,
                                                  const unsigned short* __restrict__ B2h,
                                                  const unsigned short* __restrict__ B2l,
                                                  const float* __restrict__ emb,
                                                  unsigned short* __restrict__ V,
                                                  int N, int R, int nrq) {
    const int tile = blockIdx.x / nrq;
    const int rq   = blockIdx.x % nrq;
    const int rbase = rq * 4;
    const int rcnt  = (R - rbase < 4) ? (R - rbase) : 4;
    const int n0 = tile * 128;
    __shared__ __align__(16) unsigned short Bbuf[32][512];   // 32 KB
    __shared__ __align__(16) unsigned short Us[4][1024];     // 8 KB (per-s, wave-private)
    const int t = threadIdx.x;
    const int lane = t & 63, w = t >> 6;
    const int m = lane & 15, q = lane >> 4;

    // ---- A-frags direct from global, split hi/lo in-register
    bf16x8 ah[2][2], al[2][2];
    #pragma unroll
    for (int s = 0; s < 2; ++s) {
        int n = n0 + w * 32 + s * 16 + m;
        const float* rowp = feat + (size_t)n * D;
        #pragma unroll
        for (int kb = 0; kb < 2; ++kb) {
            int d0 = kb * 32 + q * 8;
            float4 v0 = make_float4(0.f, 0.f, 0.f, 0.f), v1 = v0;
            if (n < N) { v0 = *(const float4*)(rowp + d0); v1 = *(const float4*)(rowp + d0 + 4); }
            float vals[8] = {v0.x, v0.y, v0.z, v0.w, v1.x, v1.y, v1.z, v1.w};
            bf16x8 hv, lv;
            #pragma unroll
            for (int j = 0; j < 8; ++j) {
                unsigned short h = f2bf(vals[j]);
                hv[j] = (short)h;
                lv[j] = (short)f2bf(vals[j] - bf2f(h));
            }
            ah[s][kb] = hv; al[s][kb] = lv;
        }
    }

    auto stage_half = [&](int r, int half) {
        const unsigned short* arr = half ? ((w < 2) ? B2h : B2l)
                                         : ((w < 2) ? B1h : B1l);
        const unsigned short* gp = arr + (size_t)r * 4096 + (size_t)(w & 1) * 2048 + lane * 8;
        unsigned short* lp = &Bbuf[half * 16 + (w >> 1) * 8 + (w & 1) * 4][0];
        #pragma unroll
        for (int i = 0; i < 4; ++i)
            dma16(gp + i * 512, lp + i * 512);
    };

    stage_half(rbase, 0);
    stage_half(rbase, 1);
    __syncthreads();

    for (int rr = 0; rr < rcnt; ++rr) {
        const int r = rbase + rr;
        float em[4];
        #pragma unroll
        for (int c = 0; c < 4; ++c) em[c] = emb[r * 64 + c * 16 + m];

        // ---------- GEMM1 (both s): P = feat @ W_r (3-term split), B-frags hoisted
        f32x4 acc[4][2];
        #pragma unroll
        for (int c = 0; c < 4; ++c)
            #pragma unroll
            for (int s = 0; s < 2; ++s) acc[c][s] = (f32x4){0.f, 0.f, 0.f, 0.f};
        #pragma unroll
        for (int c = 0; c < 4; ++c) {
            bf16x8 bh[2], bl[2];
            #pragma unroll
            for (int kb = 0; kb < 2; ++kb) {
                bh[kb] = *(const bf16x8*)&Bbuf[c * 2 + kb][lane * 8];
                bl[kb] = *(const bf16x8*)&Bbuf[8 + c * 2 + kb][lane * 8];
            }
            #pragma unroll
            for (int s = 0; s < 2; ++s)
                #pragma unroll
                for (int kb = 0; kb < 2; ++kb) {
                    acc[c][s] = __builtin_amdgcn_mfma_f32_16x16x32_bf16(ah[s][kb], bh[kb], acc[c][s], 0, 0, 0);
                    acc[c][s] = __builtin_amdgcn_mfma_f32_16x16x32_bf16(al[s][kb], bh[kb], acc[c][s], 0, 0, 0);
                    acc[c][s] = __builtin_amdgcn_mfma_f32_16x16x32_bf16(ah[s][kb], bl[kb], acc[c][s], 0, 0, 0);
                }
        }

        __syncthreads();                         // rows 0-15 consumed
        if (rr + 1 < rcnt) stage_half(r + 1, 0); // B1(r+1) DMA overlaps epi+GEMM2

        // ---------- per-s: epilogue -> Us, GEMM2, store
        #pragma unroll
        for (int s = 0; s < 2; ++s) {
            #pragma unroll
            for (int c = 0; c < 4; ++c) {
                int o = c * 16 + m;
                int kb2 = o >> 5;
                int q2 = (o >> 3) & 3;
                int j = o & 7;
                int Fb = kb2 * 64 + q2 * 16 + q * 4;
                #pragma unroll
                for (int i = 0; i < 4; i += 2) {
                    float t0 = fast_tanh(acc[c][s][i] + em[c]);
                    float t1 = fast_tanh(acc[c][s][i + 1] + em[c]);
                    unsigned int pk = pk2bf(t0, t1);
                    Us[w][((Fb + i) ^ q2) * 8 + j]     = (unsigned short)(pk & 0xFFFF);
                    Us[w][((Fb + i + 1) ^ q2) * 8 + j] = (unsigned short)(pk >> 16);
                }
            }

            bf16x8 ua[2];
            #pragma unroll
            for (int kb = 0; kb < 2; ++kb) {
                int F = kb * 64 + lane;
                ua[kb] = *(const bf16x8*)&Us[w][(F ^ (lane >> 4)) * 8];
            }
            f32x4 acc2[4];
            #pragma unroll
            for (int c = 0; c < 4; ++c) acc2[c] = (f32x4){0.f, 0.f, 0.f, 0.f};
            #pragma unroll
            for (int c = 0; c < 4; ++c) {
                bf16x8 bh[2], bl[2];
                #pragma unroll
                for (int kb = 0; kb < 2; ++kb) {
                    bh[kb] = *(const bf16x8*)&Bbuf[16 + c * 2 + kb][lane * 8];
                    bl[kb] = *(const bf16x8*)&Bbuf[24 + c * 2 + kb][lane * 8];
                }
                #pragma unroll
                for (int kb = 0; kb < 2; ++kb) {
                    acc2[c] = __builtin_amdgcn_mfma_f32_16x16x32_bf16(ua[kb], bh[kb], acc2[c], 0, 0, 0);
                    acc2[c] = __builtin_amdgcn_mfma_f32_16x16x32_bf16(ua[kb], bl[kb], acc2[c], 0, 0, 0);
                }
            }

            #pragma unroll
            for (int i = 0; i < 4; ++i) {
                int n = n0 + w * 32 + s * 16 + q * 4 + i;
                if (n < N) {
                    uint2 pv;
                    pv.x = pk2bf(acc2[0][i], acc2[1][i]);
                    pv.y = pk2bf(acc2[2][i], acc2[3][i]);
                    *(uint2*)&V[((size_t)n * R + r) * 64 + m * 4] = pv;
                }
            }
        }

        __syncthreads();                         // rows 16-31 consumed; half-0 DMA drained
        if (rr + 1 < rcnt) stage_half(r + 1, 1); // B2(r+1) DMA overlaps next GEMM1
    }
}

// ---------------- fused att + softmax + aggregation: 4 edges per wave-iteration.
__global__ __launch_bounds__(256) void k_fused2(const unsigned short* __restrict__ V,
                                                const float* __restrict__ feat,
                                                const int* __restrict__ offsets,
                                                const int* __restrict__ spack,
                                                float* __restrict__ h_nb,
                                                int N, int R) {
    const int lane = threadIdx.x & 63;
    const int wav  = threadIdx.x >> 6;
    const int g    = lane >> 4;
    const int k    = lane & 15;
    const int n = blockIdx.x * 4 + wav;
    __shared__ float vlds[4][1024];
    if (n >= N) return;

    const unsigned int* v32 = (const unsigned int*)(V + (size_t)n * R * D);
    #pragma unroll
    for (int j = 0; j < 8; ++j) {
        int uidx = j * 64 + lane;
        unsigned int u = v32[uidx];
        int r  = uidx >> 5;
        int k2 = uidx & 31;
        int mm = k2 >> 1;
        int cc = (k2 & 1) * 2;
        int o  = cc * 16 + mm;
        vlds[wav][r * 64 + o]      = bf2f((unsigned short)(u & 0xFFFF));
        vlds[wav][r * 64 + o + 16] = bf2f((unsigned short)(u >> 16));
    }

    const int beg = offsets[n], end = offsets[n + 1];
    float m = -INFINITY, l = 0.f;
    float4 acc = make_float4(0.f, 0.f, 0.f, 0.f);

    if (beg < end) {
        int e = beg + g;
        bool ok = e < end;
        int pk = spack[ok ? e : (end - 1)];
        float4 f = *(const float4*)&feat[(size_t)(pk & 0xFFFFF) * D + k * 4];

        for (int i = beg; i < end; i += 4) {
            const int   et  = pk >> 20;
            const float4 fc = f;
            const bool  okc = ok;
            int e2 = i + 4 + g;
            ok = e2 < end;
            pk = spack[ok ? e2 : (end - 1)];
            f = *(const float4*)&feat[(size_t)(pk & 0xFFFFF) * D + k * 4];

            float4 v = *(const float4*)&vlds[wav][et * 64 + k * 4];
            float p = fc.x * v.x + fc.y * v.y + fc.z * v.z + fc.w * v.w;
            p += __shfl_xor(p, 1, 64);
            p += __shfl_xor(p, 2, 64);
            p += __shfl_xor(p, 4, 64);
            p += __shfl_xor(p, 8, 64);
            p = okc ? p : -INFINITY;
            float tmx = fmaxf(p, __shfl_xor(p, 16, 64));
            float nm4 = fmaxf(tmx, __shfl_xor(tmx, 32, 64));
            float nm  = fmaxf(m, nm4);
            float scale = __expf(m - nm);
            float wg    = __expf(p - nm);
            float sw = wg + __shfl_xor(wg, 16, 64);
            sw += __shfl_xor(sw, 32, 64);
            l = l * scale + sw;
            acc.x = acc.x * scale + wg * fc.x;
            acc.y = acc.y * scale + wg * fc.y;
            acc.z = acc.z * scale + wg * fc.z;
            acc.w = acc.w * scale + wg * fc.w;
            m = nm;
        }
        acc.x += __shfl_xor(acc.x, 16, 64);
        acc.y += __shfl_xor(acc.y, 16, 64);
        acc.z += __shfl_xor(acc.z, 16, 64);
        acc.w += __shfl_xor(acc.w, 16, 64);
        acc.x += __shfl_xor(acc.x, 32, 64);
        acc.y += __shfl_xor(acc.y, 32, 64);
        acc.z += __shfl_xor(acc.z, 32, 64);
        acc.w += __shfl_xor(acc.w, 32, 64);
        float inv = 1.f / l;
        acc.x *= inv; acc.y *= inv; acc.z *= inv; acc.w *= inv;
    }
    if (lane < 16)
        *(float4*)&h_nb[(size_t)n * D + k * 4] = acc;
}

// ---------------- final via MFMA: out = lrelu((f+h)@W1^T) + lrelu((f*h)@W2^T)
__global__ __launch_bounds__(256, 2) void k_final(const float* __restrict__ feat,
                                                  const float* __restrict__ h_nb,
                                                  const unsigned short* __restrict__ F1h,
                                                  const unsigned short* __restrict__ F1l,
                                                  const unsigned short* __restrict__ F2h,
                                                  const unsigned short* __restrict__ F2l,
                                                  float* __restrict__ out, int N) {
    const int n0 = blockIdx.x * 128;
    __shared__ __align__(16) unsigned short Wlds[4][4096];
    const int t = threadIdx.x;
    const int lane = t & 63, w = t >> 6;
    const int m = lane & 15, q = lane >> 4;

    const unsigned short* warr = (w == 0) ? F1h : (w == 1) ? F1l : (w == 2) ? F2h : F2l;
    #pragma unroll
    for (int i = 0; i < 8; ++i)
        dma16(warr + i * 512 + lane * 8, &Wlds[w][i * 512]);

    bf16x8 sh[2][2], sl[2][2], ph[2][2], pl[2][2];
    #pragma unroll
    for (int s = 0; s < 2; ++s) {
        int n = n0 + w * 32 + s * 16 + m;
        const float* fp = feat + (size_t)n * D;
        const float* hp = h_nb + (size_t)n * D;
        #pragma unroll
        for (int kb = 0; kb < 2; ++kb) {
            int d0 = kb * 32 + q * 8;
            float4 f0 = make_float4(0.f, 0.f, 0.f, 0.f), f1 = f0, h0 = f0, h1 = f0;
            if (n < N) {
                f0 = *(const float4*)(fp + d0); f1 = *(const float4*)(fp + d0 + 4);
                h0 = *(const float4*)(hp + d0); h1 = *(const float4*)(hp + d0 + 4);
            }
            float fv[8] = {f0.x, f0.y, f0.z, f0.w, f1.x, f1.y, f1.z, f1.w};
            float hv[8] = {h0.x, h0.y, h0.z, h0.w, h1.x, h1.y, h1.z, h1.w};
            bf16x8 a, b, c2, d2;
            #pragma unroll
            for (int j = 0; j < 8; ++j) {
                float xs = fv[j] + hv[j];
                float xp = fv[j] * hv[j];
                unsigned short hs = f2bf(xs);
                unsigned short hp2 = f2bf(xp);
                a[j]  = (short)hs;
                b[j]  = (short)f2bf(xs - bf2f(hs));
                c2[j] = (short)hp2;
                d2[j] = (short)f2bf(xp - bf2f(hp2));
            }
            sh[s][kb] = a; sl[s][kb] = b; ph[s][kb] = c2; pl[s][kb] = d2;
        }
    }
    __syncthreads();

    f32x4 a1[4][2], a2[4][2];
    #pragma unroll
    for (int c = 0; c < 4; ++c)
        #pragma unroll
        for (int s = 0; s < 2; ++s) {
            a1[c][s] = (f32x4){0.f, 0.f, 0.f, 0.f};
            a2[c][s] = (f32x4){0.f, 0.f, 0.f, 0.f};
        }
    #pragma unroll
    for (int c = 0; c < 4; ++c) {
        bf16x8 b1h[2], b1l[2], b2h[2], b2l[2];
        #pragma unroll
        for (int kb = 0; kb < 2; ++kb) {
            int o = (c * 2 + kb) * 512 + lane * 8;
            b1h[kb] = *(const bf16x8*)&Wlds[0][o];
            b1l[kb] = *(const bf16x8*)&Wlds[1][o];
            b2h[kb] = *(const bf16x8*)&Wlds[2][o];
            b2l[kb] = *(const bf16x8*)&Wlds[3][o];
        }
        #pragma unroll
        for (int kb = 0; kb < 2; ++kb)
            #pragma unroll
            for (int s = 0; s < 2; ++s) {
                a1[c][s] = __builtin_amdgcn_mfma_f32_16x16x32_bf16(sh[s][kb], b1h[kb], a1[c][s], 0, 0, 0);
                a1[c][s] = __builtin_amdgcn_mfma_f32_16x16x32_bf16(sl[s][kb], b1h[kb], a1[c][s], 0, 0, 0);
                a1[c][s] = __builtin_amdgcn_mfma_f32_16x16x32_bf16(sh[s][kb], b1l[kb], a1[c][s], 0, 0, 0);
                a2[c][s] = __builtin_amdgcn_mfma_f32_16x16x32_bf16(ph[s][kb], b2h[kb], a2[c][s], 0, 0, 0);
                a2[c][s] = __builtin_amdgcn_mfma_f32_16x16x32_bf16(pl[s][kb], b2h[kb], a2[c][s], 0, 0, 0);
                a2[c][s] = __builtin_amdgcn_mfma_f32_16x16x32_bf16(ph[s][kb], b2l[kb], a2[c][s], 0, 0, 0);
            }
    }

    #pragma unroll
    for (int s = 0; s < 2; ++s)
        #pragma unroll
        for (int i = 0; i < 4; ++i) {
            int n = n0 + w * 32 + s * 16 + q * 4 + i;
            if (n < N) {
                #pragma unroll
                for (int c = 0; c < 4; ++c) {
                    float o1 = a1[c][s][i];
                    float o2 = a2[c][s][i];
                    o1 = (o1 > 0.f) ? o1 : 0.01f * o1;
                    o2 = (o2 > 0.f) ? o2 : 0.01f * o2;
                    out[(size_t)n * D + c * 16 + m] = o1 + o2;
                }
            }
        }
}

extern "C" void kernel_launch(void* const* d_in, const int* in_sizes, int n_in,
                              void* d_out, int out_size, void* d_ws, size_t ws_size,
                              hipStream_t stream) {
    const float* feat  = (const float*)d_in[0];
    const float* relW  = (const float*)d_in[1];
    const float* relE  = (const float*)d_in[2];
    const float* W1    = (const float*)d_in[3];
    const float* W2    = (const float*)d_in[4];
    const int*   src   = (const int*)d_in[5];
    const int*   dst   = (const int*)d_in[6];
    const int*   etype = (const int*)d_in[7];
    float* out = (float*)d_out;

    const int N = in_sizes[0] / D;
    const int R = in_sizes[2] / D;
    const int E = in_sizes[5];

    char* w = (char*)d_ws;
    size_t off = 0;
    auto alloc = [&](size_t bytes) -> void* {
        void* p = w + off;
        off = (off + bytes + 255) & ~(size_t)255;
        return p;
    };
    unsigned short* varr = (unsigned short*)alloc((size_t)N * R * D * sizeof(unsigned short));
    float* h_nb   = (float*)alloc((size_t)N * D * sizeof(float));
    int* offsets  = (int*)alloc((size_t)(N + 1) * sizeof(int));
    int* bsum     = (int*)alloc(2048 * sizeof(int));
    int* bofs     = (int*)alloc(2048 * sizeof(int));
    int* spack    = (int*)alloc((size_t)E * sizeof(int));
    size_t wfrag = (size_t)R * 4 * 2 * 64 * 8;
    unsigned short* B1h = (unsigned short*)alloc(wfrag * sizeof(unsigned short));
    unsigned short* B1l = (unsigned short*)alloc(wfrag * sizeof(unsigned short));
    unsigned short* B2h = (unsigned short*)alloc(wfrag * sizeof(unsigned short));
    unsigned short* B2l = (unsigned short*)alloc(wfrag * sizeof(unsigned short));
    unsigned short* F1h = (unsigned short*)alloc(4096 * sizeof(unsigned short));
    unsigned short* F1l = (unsigned short*)alloc(4096 * sizeof(unsigned short));
    unsigned short* F2h = (unsigned short*)alloc(4096 * sizeof(unsigned short));
    unsigned short* F2l = (unsigned short*)alloc(4096 * sizeof(unsigned short));
    (void)ws_size; (void)n_in; (void)out_size;

    // ---- CSR scratch aliases varr (dead before k_projv writes varr)
    const int NBUK = (N + 127) >> 7;           // buckets of 128 nodes (<=1024)
    const int CH   = (E + NB3 - 1) / NB3;      // edges per chunk
    const int L    = NBUK << 8;                // cnt/csc length (NB3=256)
    int* ebuf = (int*)varr;                    // E ints
    int* cnt  = ebuf + E;                      // L ints
    int* tsc  = cnt + L;                       // L ints
    int* csc  = tsc + L;                       // L+1 ints
    const int NBscan = (L + 1023) / 1024;

    const int nrq = (R + 3) / 4;               // r-quarters per tile
    const int ntiles = (N + 127) / 128;

    k_wsplit<<<(2 * R * 512 + 255) / 256, 256, 0, stream>>>(relW, B1h, B1l, B2h, B2l, R);
    k_wsplit2<<<4, 256, 0, stream>>>(W1, W2, F1h, F1l, F2h, F2l);
    k_bcount<<<NB3, 256, 0, stream>>>(dst, cnt, E, CH, NBUK);
    k_scan1<<<NBscan, 1024, 0, stream>>>(cnt, tsc, bsum, L);
    k_scan2<<<1, 1024, 0, stream>>>(bsum, bofs, NBscan);
    k_scanout<<<(L + 1 + 255) / 256, 256, 0, stream>>>(tsc, bofs, csc, L);
    k_bscatter<<<NB3, 256, 0, stream>>>(src, dst, etype, csc, ebuf, E, CH, NBUK);
    k_bcsr<<<NBUK, 256, 0, stream>>>(ebuf, csc, offsets, spack, N, E, NBUK);
    k_projv<<<ntiles * nrq, 256, 0, stream>>>(feat, B1h, B1l, B2h, B2l, relE, varr, N, R, nrq);
    k_fused2<<<(N + 3) / 4, 256, 0, stream>>>(varr, feat, offsets, spack, h_nb, N, R);
    k_final<<<(N + 127) / 128, 256, 0, stream>>>(feat, h_nb, F1h, F1l, F2h, F2l, out, N);
}